// Round 1
// baseline (563.452 us; speedup 1.0000x reference)
//
#include <hip/hip_runtime.h>

typedef __attribute__((ext_vector_type(8))) short short8;
typedef __attribute__((ext_vector_type(4))) float floatx4;
typedef __attribute__((ext_vector_type(4))) unsigned int uintx4;

__device__ __forceinline__ short f2bf(float f) {
    unsigned u = __builtin_bit_cast(unsigned, f);
    u = (u + 0x7FFFu + ((u >> 16) & 1u)) >> 16;
    return (short)u;
}

// ---------------------------------------------------------------------------
// Workspace layout (bf16 element offsets):
//   w1T0=0, w1T1=65536, w1T2=196608, w2T0=458752, w2T1=524288, w2T2=589824
//   xg0 = 655360  (4096*256)
//   xg1 = 1703936 (4096*512)
//   xg2 = 3801088 (4096*1024)   end = 7995392 elems ~= 16 MB
// ---------------------------------------------------------------------------

__global__ __launch_bounds__(256) void prep_w(
    const float* __restrict__ w10, const float* __restrict__ w11, const float* __restrict__ w12,
    const float* __restrict__ w20, const float* __restrict__ w21, const float* __restrict__ w22,
    unsigned short* __restrict__ wsb)
{
    __shared__ float tile[32][33];
    int blk = blockIdx.x;
    const float* in; unsigned short* out; int K, t0;
    if (blk < 64)       { in = w10; out = wsb;          K = 256;  t0 = 0; }
    else if (blk < 192) { in = w11; out = wsb + 65536;  K = 512;  t0 = 64; }
    else if (blk < 448) { in = w12; out = wsb + 196608; K = 1024; t0 = 192; }
    else if (blk < 512) { in = w20; out = wsb + 458752; K = 256;  t0 = 448; }
    else if (blk < 576) { in = w21; out = wsb + 524288; K = 256;  t0 = 512; }
    else                { in = w22; out = wsb + 589824; K = 256;  t0 = 576; }
    int tile_id = blk - t0;
    int tk = K >> 5;
    int k0 = (tile_id % tk) << 5;
    int n0 = (tile_id / tk) << 5;
    int t = threadIdx.x;
    int j = t & 31, i0 = (t >> 5) << 2;
    #pragma unroll
    for (int u = 0; u < 4; u++)
        tile[i0 + u][j] = in[(size_t)(k0 + i0 + u) * 256 + (n0 + j)];
    __syncthreads();
    int kf = t & 31, nf0 = (t >> 5) << 2;
    #pragma unroll
    for (int u = 0; u < 4; u++)
        out[(size_t)(n0 + nf0 + u) * K + (k0 + kf)] = (unsigned short)f2bf(tile[kf][nf0 + u]);
}

// ---------------------------------------------------------------------------
// Dedicated scatter-gather: feat[b, c, s] (stride-HW scattered reads) ->
// compact bf16 x[4096][C] (coalesced 16B stores). One 8-channel chunk per
// thread; no LDS, no barriers -> maximal outstanding-load pressure.
// Grid: 3584 blocks x 256 thr. scale0: 512 blks, scale1: 1024, scale2: 2048.
// ---------------------------------------------------------------------------
__global__ __launch_bounds__(256) void gather_x(
    const float* __restrict__ feat0, const float* __restrict__ feat1, const float* __restrict__ feat2,
    const int* __restrict__ pid0, const int* __restrict__ pid1, const int* __restrict__ pid2,
    unsigned short* __restrict__ wsb)
{
    int blk = blockIdx.x;
    const float* feat; const int* pid; unsigned short* xg;
    int lblk, cl8, HW;   // cl8 = log2(C/8)
    if (blk < 512)       { feat = feat0; pid = pid0; lblk = blk;        cl8 = 5; HW = 16384; xg = wsb + 655360; }
    else if (blk < 1536) { feat = feat1; pid = pid1; lblk = blk - 512;  cl8 = 6; HW = 4096;  xg = wsb + 1703936; }
    else                 { feat = feat2; pid = pid2; lblk = blk - 1536; cl8 = 7; HW = 1024;  xg = wsb + 3801088; }

    int g   = (lblk << 8) + threadIdx.x;       // global chunk id within scale
    int row = g >> cl8;                        // 0..4095  (b*256 + p)
    int gk  = (g & ((1 << cl8) - 1)) << 3;     // channel start of this chunk
    int b = row >> 8, p = row & 255;
    int s = pid[p];
    int C = 8 << cl8;

    const float* gp = feat + (size_t)b * ((size_t)C * HW) + (size_t)gk * HW + s;
    float v[8];
    #pragma unroll
    for (int j = 0; j < 8; j++) v[j] = gp[(size_t)j * HW];   // 8 independent scattered loads
    short8 sv;
    #pragma unroll
    for (int j = 0; j < 8; j++) sv[j] = f2bf(v[j]);
    *(short8*)(xg + ((size_t)row << (cl8 + 3)) + gk) = sv;   // coalesced 16B store
}

// ---------------------------------------------------------------------------
// MLP(2-layer, relu) + L2-normalize, reading compact bf16 x from workspace.
// Block: 32 rows x 256 cols. 4 waves: wave w -> rows (w&1)*16, cols (w>>1)*128.
// LDS (bytes):  ws  [256][72] bf16 = 36864   @ 0      (w-tile, restaged per chunk)
//               xs  [ 32][72] bf16 =  4608   @ 36864  (x tile, GEMM1)
//               hs  [ 32][264] bf16 = 16896  @ 36864  (h tile, GEMM2; reuses xs)
//               rs  [32] f32        =  128   @ 53760  (row sumsq)
// ---------------------------------------------------------------------------
__global__ __launch_bounds__(256, 2) void fused_mlp(
    const float* __restrict__ b1_0, const float* __restrict__ b1_1, const float* __restrict__ b1_2,
    const float* __restrict__ b2_0, const float* __restrict__ b2_1, const float* __restrict__ b2_2,
    const unsigned short* __restrict__ wsb,
    float* __restrict__ out)
{
    __shared__ __align__(16) unsigned short smem[26944];
    unsigned short* wsS = smem;            // 256*72
    unsigned short* xs  = smem + 18432;    // 32*72
    unsigned short* hs  = smem + 18432;    // 32*264
    float* rs = (float*)(smem + 26880);    // 32 floats

    int blk = blockIdx.x;
    int scale = 2 - (blk >> 7);            // big-K blocks dispatched first
    int mblk = blk & 127;

    const float* b1; const float* b2;
    const unsigned short* w1T; const unsigned short* w2T; const unsigned short* xg;
    int C; size_t outBase;
    if (scale == 0) { b1 = b1_0; b2 = b2_0; w1T = wsb;          w2T = wsb + 458752;
                      xg = wsb + 655360;  C = 256;  outBase = 0; }
    else if (scale == 1) { b1 = b1_1; b2 = b2_1; w1T = wsb + 65536;  w2T = wsb + 524288;
                      xg = wsb + 1703936; C = 512;  outBase = 1048576; }
    else            { b1 = b1_2; b2 = b2_2; w1T = wsb + 196608; w2T = wsb + 589824;
                      xg = wsb + 3801088; C = 1024; outBase = 2097152; }

    int t = threadIdx.x;
    int wid = t >> 6, lane = t & 63, quad = lane >> 4, l15 = lane & 15;
    int r0 = (wid & 1) << 4;          // row offset of this wave
    int c0 = (wid >> 1) << 7;         // col offset of this wave

    // x staging assignment: thread t copies row gr, k-run [gk, gk+8)
    int gr = t >> 3;                  // 0..31
    int gk = (t & 7) << 3;            // 0,8,...,56
    int row_g = (mblk << 5) + gr;
    const unsigned short* xrow = xg + (size_t)row_g * C;

    floatx4 acc[8];
    #pragma unroll
    for (int f = 0; f < 8; f++) acc[f] = (floatx4){0.f, 0.f, 0.f, 0.f};

    // ---------------- GEMM1: x[32,C] @ w1[C,256] ----------------
    for (int kc = 0; kc < C; kc += 64) {
        // stage x chunk (coalesced 16B copy from compact buffer)
        *(short8*)(xs + gr * 72 + gk) = *(const short8*)(xrow + kc + gk);
        // stage w1T chunk: thread t = row n, 128B contiguous
        {
            const uintx4* src = (const uintx4*)(w1T + (size_t)t * C + kc);
            uintx4* dst = (uintx4*)(wsS + t * 72);
            #pragma unroll
            for (int j2 = 0; j2 < 8; j2++) dst[j2] = src[j2];
        }
        __syncthreads();
        const unsigned short* aRow = xs + (r0 + l15) * 72;
        const unsigned short* bRow = wsS + (c0 + l15) * 72;
        #pragma unroll
        for (int ks = 0; ks < 2; ks++) {
            short8 af = *(const short8*)(aRow + ks * 32 + quad * 8);
            #pragma unroll
            for (int f = 0; f < 8; f++) {
                short8 bf = *(const short8*)(bRow + f * (16 * 72) + ks * 32 + quad * 8);
                acc[f] = __builtin_amdgcn_mfma_f32_16x16x32_bf16(af, bf, acc[f], 0, 0, 0);
            }
        }
        __syncthreads();
    }

    // ---------------- h = relu(acc + b1) -> LDS (bf16) ----------------
    {
        float bias1[8];
        #pragma unroll
        for (int f = 0; f < 8; f++) bias1[f] = b1[c0 + f * 16 + l15];
        #pragma unroll
        for (int f = 0; f < 8; f++)
            #pragma unroll
            for (int reg = 0; reg < 4; reg++) {
                float h = fmaxf(acc[f][reg] + bias1[f], 0.f);
                hs[(r0 + quad * 4 + reg) * 264 + (c0 + f * 16 + l15)] = (unsigned short)f2bf(h);
            }
    }

    // ---------------- GEMM2: h[32,256] @ w2[256,256] ----------------
    #pragma unroll
    for (int f = 0; f < 8; f++) acc[f] = (floatx4){0.f, 0.f, 0.f, 0.f};
    const unsigned short* hA = hs + (r0 + l15) * 264;
    for (int kc = 0; kc < 256; kc += 64) {
        {
            const uintx4* src = (const uintx4*)(w2T + (size_t)t * 256 + kc);
            uintx4* dst = (uintx4*)(wsS + t * 72);
            #pragma unroll
            for (int j2 = 0; j2 < 8; j2++) dst[j2] = src[j2];
        }
        __syncthreads();
        const unsigned short* bRow = wsS + (c0 + l15) * 72;
        #pragma unroll
        for (int ks = 0; ks < 2; ks++) {
            short8 af = *(const short8*)(hA + kc + ks * 32 + quad * 8);
            #pragma unroll
            for (int f = 0; f < 8; f++) {
                short8 bf = *(const short8*)(bRow + f * (16 * 72) + ks * 32 + quad * 8);
                acc[f] = __builtin_amdgcn_mfma_f32_16x16x32_bf16(af, bf, acc[f], 0, 0, 0);
            }
        }
        __syncthreads();
    }

    // ---------------- epilogue: y = acc + b2; y / (||y|| + 1e-7) ----------------
    {
        float bias2[8];
        #pragma unroll
        for (int f = 0; f < 8; f++) bias2[f] = b2[c0 + f * 16 + l15];
        float psq[4] = {0.f, 0.f, 0.f, 0.f};
        #pragma unroll
        for (int f = 0; f < 8; f++)
            #pragma unroll
            for (int reg = 0; reg < 4; reg++) {
                float yv = acc[f][reg] + bias2[f];
                acc[f][reg] = yv;
                psq[reg] += yv * yv;
            }
        // reduce across the 16 lanes of each quad
        #pragma unroll
        for (int m = 1; m < 16; m <<= 1)
            #pragma unroll
            for (int reg = 0; reg < 4; reg++)
                psq[reg] += __shfl_xor(psq[reg], m, 16);

        if (t < 32) rs[t] = 0.f;
        __syncthreads();
        if (l15 == 0) {
            #pragma unroll
            for (int reg = 0; reg < 4; reg++)
                atomicAdd(&rs[r0 + quad * 4 + reg], psq[reg]);
        }
        __syncthreads();

        #pragma unroll
        for (int f = 0; f < 8; f++)
            #pragma unroll
            for (int reg = 0; reg < 4; reg++) {
                int row = r0 + quad * 4 + reg;
                float inv = 1.f / (sqrtf(rs[row]) + 1e-7f);
                out[outBase + (size_t)((mblk << 5) + row) * 256 + (c0 + f * 16 + l15)] =
                    acc[f][reg] * inv;
            }
    }
}

extern "C" void kernel_launch(void* const* d_in, const int* in_sizes, int n_in,
                              void* d_out, int out_size, void* d_ws, size_t ws_size,
                              hipStream_t stream)
{
    (void)n_in; (void)out_size; (void)ws_size;
    bool dict = (in_sizes[1] == 256);
    const float *feat[3], *w1[3], *b1[3], *w2[3], *b2[3];
    const int* pid[3];
    for (int i = 0; i < 3; i++) {
        if (dict) {
            feat[i] = (const float*)d_in[i * 6 + 0];
            pid[i]  = (const int*)  d_in[i * 6 + 1];
            w1[i]   = (const float*)d_in[i * 6 + 2];
            b1[i]   = (const float*)d_in[i * 6 + 3];
            w2[i]   = (const float*)d_in[i * 6 + 4];
            b2[i]   = (const float*)d_in[i * 6 + 5];
        } else {
            feat[i] = (const float*)d_in[i];
            pid[i]  = (const int*)  d_in[3 + i];
            w1[i]   = (const float*)d_in[6 + 4 * i + 0];
            b1[i]   = (const float*)d_in[6 + 4 * i + 1];
            w2[i]   = (const float*)d_in[6 + 4 * i + 2];
            b2[i]   = (const float*)d_in[6 + 4 * i + 3];
        }
    }
    unsigned short* wsb = (unsigned short*)d_ws;   // needs ~16 MB of workspace
    prep_w<<<640, 256, 0, stream>>>(w1[0], w1[1], w1[2], w2[0], w2[1], w2[2], wsb);
    gather_x<<<3584, 256, 0, stream>>>(feat[0], feat[1], feat[2],
                                       pid[0], pid[1], pid[2], wsb);
    fused_mlp<<<384, 256, 0, stream>>>(b1[0], b1[1], b1[2],
                                       b2[0], b2[1], b2[2],
                                       wsb, (float*)d_out);
}

// Round 2
// 533.046 us; speedup vs baseline: 1.0570x; 1.0570x over previous
//
#include <hip/hip_runtime.h>

typedef __attribute__((ext_vector_type(8))) short short8;
typedef __attribute__((ext_vector_type(4))) float floatx4;
typedef __attribute__((ext_vector_type(4))) unsigned int uintx4;

__device__ __forceinline__ short f2bf(float f) {
    unsigned u = __builtin_bit_cast(unsigned, f);
    u = (u + 0x7FFFu + ((u >> 16) & 1u)) >> 16;
    return (short)u;
}

// ---------------------------------------------------------------------------
// Workspace layout (bf16 element offsets):
//   w1T0=0, w1T1=65536, w1T2=196608, w2T0=458752, w2T1=524288, w2T2=589824
//   xg0 = 655360  (4096*256)
//   xg1 = 1703936 (4096*512)
//   xg2 = 3801088 (4096*1024)
//   sorted pid (int2, 3 scales x 256) @ bf16 offset 7995392 (byte 15990784)
// ---------------------------------------------------------------------------

// Bitonic sort of 256 (s, p) pairs per scale, ascending by s.
__global__ __launch_bounds__(256) void sort_pid(
    const int* __restrict__ pid0, const int* __restrict__ pid1, const int* __restrict__ pid2,
    unsigned short* __restrict__ wsb)
{
    __shared__ int ks[256];
    __shared__ int vs[256];
    const int* pid = (blockIdx.x == 0) ? pid0 : (blockIdx.x == 1) ? pid1 : pid2;
    int t = threadIdx.x;
    ks[t] = pid[t];
    vs[t] = t;
    __syncthreads();
    for (int k = 2; k <= 256; k <<= 1) {
        for (int j = k >> 1; j > 0; j >>= 1) {
            int ixj = t ^ j;
            if (ixj > t) {
                int a = ks[t], b = ks[ixj];
                bool asc = ((t & k) == 0);
                if (asc ? (a > b) : (a < b)) {
                    ks[t] = b; ks[ixj] = a;
                    int va = vs[t]; vs[t] = vs[ixj]; vs[ixj] = va;
                }
            }
            __syncthreads();
        }
    }
    int2* sp = (int2*)(wsb + 7995392) + blockIdx.x * 256;
    sp[t] = make_int2(ks[t], vs[t]);
}

// ---------------------------------------------------------------------------
// Merged: blocks [0,640) transpose+cast weights (overlaps with gather);
// blocks [640,4224) do the scatter-gather in SORTED-s row order with an
// XCD-chunked block swizzle so samples sharing a cache line are processed
// by adjacent blocks on the SAME XCD (one L2 fetch serves all of them).
// ---------------------------------------------------------------------------
__global__ __launch_bounds__(256) void gather_prep(
    const float* __restrict__ feat0, const float* __restrict__ feat1, const float* __restrict__ feat2,
    const float* __restrict__ w10, const float* __restrict__ w11, const float* __restrict__ w12,
    const float* __restrict__ w20, const float* __restrict__ w21, const float* __restrict__ w22,
    unsigned short* __restrict__ wsb)
{
    __shared__ float tile[32][33];
    int blk = blockIdx.x;
    int t = threadIdx.x;

    if (blk < 640) {
        // ---- weight transpose+cast fp32 w[K][256] -> bf16 wT[256][K] ----
        const float* in; unsigned short* out; int K, t0;
        if (blk < 64)       { in = w10; out = wsb;          K = 256;  t0 = 0; }
        else if (blk < 192) { in = w11; out = wsb + 65536;  K = 512;  t0 = 64; }
        else if (blk < 448) { in = w12; out = wsb + 196608; K = 1024; t0 = 192; }
        else if (blk < 512) { in = w20; out = wsb + 458752; K = 256;  t0 = 448; }
        else if (blk < 576) { in = w21; out = wsb + 524288; K = 256;  t0 = 512; }
        else                { in = w22; out = wsb + 589824; K = 256;  t0 = 576; }
        int tile_id = blk - t0;
        int tk = K >> 5;
        int k0 = (tile_id % tk) << 5;
        int n0 = (tile_id / tk) << 5;
        int j = t & 31, i0 = (t >> 5) << 2;
        #pragma unroll
        for (int u = 0; u < 4; u++)
            tile[i0 + u][j] = in[(size_t)(k0 + i0 + u) * 256 + (n0 + j)];
        __syncthreads();
        int kf = t & 31, nf0 = (t >> 5) << 2;
        #pragma unroll
        for (int u = 0; u < 4; u++)
            out[(size_t)(n0 + nf0 + u) * K + (k0 + kf)] = (unsigned short)f2bf(tile[kf][nf0 + u]);
        return;
    }

    // ---- gather ----
    blk -= 640;
    const float* feat; const int2* sp; unsigned short* xg;
    int lblk, cl8, HW, n;     // cl8 = log2(C/8), n = blocks for this scale
    const int2* spb = (const int2*)(wsb + 7995392);
    if (blk < 512)       { feat = feat0; sp = spb;       lblk = blk;        cl8 = 5; HW = 16384; n = 512;  xg = wsb + 655360; }
    else if (blk < 1536) { feat = feat1; sp = spb + 256; lblk = blk - 512;  cl8 = 6; HW = 4096;  n = 1024; xg = wsb + 1703936; }
    else                 { feat = feat2; sp = spb + 512; lblk = blk - 1536; cl8 = 7; HW = 1024;  n = 2048; xg = wsb + 3801088; }

    // XCD-chunked swizzle: dispatch round-robins blk across 8 XCDs; remap so
    // XCD x owns the contiguous sorted-row chunk [x*n/8, (x+1)*n/8).
    lblk = (lblk & 7) * (n >> 3) + (lblk >> 3);

    int g   = (lblk << 8) + t;                 // global chunk id within scale
    int row = g >> cl8;                        // sorted-order row: b*256 + p'
    int gk  = (g & ((1 << cl8) - 1)) << 3;     // channel start of this chunk
    int b = row >> 8, pp = row & 255;
    int2 e = sp[pp];                           // (s sorted ascending, original p)
    int s = e.x, op = e.y;
    int C = 8 << cl8;

    const float* gp = feat + (size_t)b * ((size_t)C * HW) + (size_t)gk * HW + s;
    float v[8];
    #pragma unroll
    for (int j = 0; j < 8; j++) v[j] = gp[(size_t)j * HW];   // 8 independent scattered loads
    short8 sv;
    #pragma unroll
    for (int j = 0; j < 8; j++) sv[j] = f2bf(v[j]);
    *(short8*)(xg + (size_t)(b * 256 + op) * C + gk) = sv;   // 16B store to original row slot
}

// ---------------------------------------------------------------------------
// MLP(2-layer, relu) + L2-normalize, reading compact bf16 x from workspace.
// Block: 32 rows x 256 cols. 4 waves: wave w -> rows (w&1)*16, cols (w>>1)*128.
// ---------------------------------------------------------------------------
__global__ __launch_bounds__(256, 2) void fused_mlp(
    const float* __restrict__ b1_0, const float* __restrict__ b1_1, const float* __restrict__ b1_2,
    const float* __restrict__ b2_0, const float* __restrict__ b2_1, const float* __restrict__ b2_2,
    const unsigned short* __restrict__ wsb,
    float* __restrict__ out)
{
    __shared__ __align__(16) unsigned short smem[26944];
    unsigned short* wsS = smem;            // 256*72
    unsigned short* xs  = smem + 18432;    // 32*72
    unsigned short* hs  = smem + 18432;    // 32*264
    float* rs = (float*)(smem + 26880);    // 32 floats

    int blk = blockIdx.x;
    int scale = 2 - (blk >> 7);            // big-K blocks dispatched first
    int mblk = blk & 127;

    const float* b1; const float* b2;
    const unsigned short* w1T; const unsigned short* w2T; const unsigned short* xg;
    int C; size_t outBase;
    if (scale == 0) { b1 = b1_0; b2 = b2_0; w1T = wsb;          w2T = wsb + 458752;
                      xg = wsb + 655360;  C = 256;  outBase = 0; }
    else if (scale == 1) { b1 = b1_1; b2 = b2_1; w1T = wsb + 65536;  w2T = wsb + 524288;
                      xg = wsb + 1703936; C = 512;  outBase = 1048576; }
    else            { b1 = b1_2; b2 = b2_2; w1T = wsb + 196608; w2T = wsb + 589824;
                      xg = wsb + 3801088; C = 1024; outBase = 2097152; }

    int t = threadIdx.x;
    int wid = t >> 6, lane = t & 63, quad = lane >> 4, l15 = lane & 15;
    int r0 = (wid & 1) << 4;          // row offset of this wave
    int c0 = (wid >> 1) << 7;         // col offset of this wave

    int gr = t >> 3;                  // 0..31
    int gk = (t & 7) << 3;            // 0,8,...,56
    int row_g = (mblk << 5) + gr;
    const unsigned short* xrow = xg + (size_t)row_g * C;

    floatx4 acc[8];
    #pragma unroll
    for (int f = 0; f < 8; f++) acc[f] = (floatx4){0.f, 0.f, 0.f, 0.f};

    // ---------------- GEMM1: x[32,C] @ w1[C,256] ----------------
    for (int kc = 0; kc < C; kc += 64) {
        *(short8*)(xs + gr * 72 + gk) = *(const short8*)(xrow + kc + gk);
        {
            const uintx4* src = (const uintx4*)(w1T + (size_t)t * C + kc);
            uintx4* dst = (uintx4*)(wsS + t * 72);
            #pragma unroll
            for (int j2 = 0; j2 < 8; j2++) dst[j2] = src[j2];
        }
        __syncthreads();
        const unsigned short* aRow = xs + (r0 + l15) * 72;
        const unsigned short* bRow = wsS + (c0 + l15) * 72;
        #pragma unroll
        for (int ks = 0; ks < 2; ks++) {
            short8 af = *(const short8*)(aRow + ks * 32 + quad * 8);
            #pragma unroll
            for (int f = 0; f < 8; f++) {
                short8 bf = *(const short8*)(bRow + f * (16 * 72) + ks * 32 + quad * 8);
                acc[f] = __builtin_amdgcn_mfma_f32_16x16x32_bf16(af, bf, acc[f], 0, 0, 0);
            }
        }
        __syncthreads();
    }

    // ---------------- h = relu(acc + b1) -> LDS (bf16) ----------------
    {
        float bias1[8];
        #pragma unroll
        for (int f = 0; f < 8; f++) bias1[f] = b1[c0 + f * 16 + l15];
        #pragma unroll
        for (int f = 0; f < 8; f++)
            #pragma unroll
            for (int reg = 0; reg < 4; reg++) {
                float h = fmaxf(acc[f][reg] + bias1[f], 0.f);
                hs[(r0 + quad * 4 + reg) * 264 + (c0 + f * 16 + l15)] = (unsigned short)f2bf(h);
            }
    }

    // ---------------- GEMM2: h[32,256] @ w2[256,256] ----------------
    #pragma unroll
    for (int f = 0; f < 8; f++) acc[f] = (floatx4){0.f, 0.f, 0.f, 0.f};
    const unsigned short* hA = hs + (r0 + l15) * 264;
    for (int kc = 0; kc < 256; kc += 64) {
        {
            const uintx4* src = (const uintx4*)(w2T + (size_t)t * 256 + kc);
            uintx4* dst = (uintx4*)(wsS + t * 72);
            #pragma unroll
            for (int j2 = 0; j2 < 8; j2++) dst[j2] = src[j2];
        }
        __syncthreads();
        const unsigned short* bRow = wsS + (c0 + l15) * 72;
        #pragma unroll
        for (int ks = 0; ks < 2; ks++) {
            short8 af = *(const short8*)(hA + kc + ks * 32 + quad * 8);
            #pragma unroll
            for (int f = 0; f < 8; f++) {
                short8 bf = *(const short8*)(bRow + f * (16 * 72) + ks * 32 + quad * 8);
                acc[f] = __builtin_amdgcn_mfma_f32_16x16x32_bf16(af, bf, acc[f], 0, 0, 0);
            }
        }
        __syncthreads();
    }

    // ---------------- epilogue: y = acc + b2; y / (||y|| + 1e-7) ----------------
    {
        float bias2[8];
        #pragma unroll
        for (int f = 0; f < 8; f++) bias2[f] = b2[c0 + f * 16 + l15];
        float psq[4] = {0.f, 0.f, 0.f, 0.f};
        #pragma unroll
        for (int f = 0; f < 8; f++)
            #pragma unroll
            for (int reg = 0; reg < 4; reg++) {
                float yv = acc[f][reg] + bias2[f];
                acc[f][reg] = yv;
                psq[reg] += yv * yv;
            }
        #pragma unroll
        for (int m = 1; m < 16; m <<= 1)
            #pragma unroll
            for (int reg = 0; reg < 4; reg++)
                psq[reg] += __shfl_xor(psq[reg], m, 16);

        if (t < 32) rs[t] = 0.f;
        __syncthreads();
        if (l15 == 0) {
            #pragma unroll
            for (int reg = 0; reg < 4; reg++)
                atomicAdd(&rs[r0 + quad * 4 + reg], psq[reg]);
        }
        __syncthreads();

        #pragma unroll
        for (int f = 0; f < 8; f++)
            #pragma unroll
            for (int reg = 0; reg < 4; reg++) {
                int row = r0 + quad * 4 + reg;
                float inv = 1.f / (sqrtf(rs[row]) + 1e-7f);
                out[outBase + (size_t)((mblk << 5) + row) * 256 + (c0 + f * 16 + l15)] =
                    acc[f][reg] * inv;
            }
    }
}

extern "C" void kernel_launch(void* const* d_in, const int* in_sizes, int n_in,
                              void* d_out, int out_size, void* d_ws, size_t ws_size,
                              hipStream_t stream)
{
    (void)n_in; (void)out_size; (void)ws_size;
    bool dict = (in_sizes[1] == 256);
    const float *feat[3], *w1[3], *b1[3], *w2[3], *b2[3];
    const int* pid[3];
    for (int i = 0; i < 3; i++) {
        if (dict) {
            feat[i] = (const float*)d_in[i * 6 + 0];
            pid[i]  = (const int*)  d_in[i * 6 + 1];
            w1[i]   = (const float*)d_in[i * 6 + 2];
            b1[i]   = (const float*)d_in[i * 6 + 3];
            w2[i]   = (const float*)d_in[i * 6 + 4];
            b2[i]   = (const float*)d_in[i * 6 + 5];
        } else {
            feat[i] = (const float*)d_in[i];
            pid[i]  = (const int*)  d_in[3 + i];
            w1[i]   = (const float*)d_in[6 + 4 * i + 0];
            b1[i]   = (const float*)d_in[6 + 4 * i + 1];
            w2[i]   = (const float*)d_in[6 + 4 * i + 2];
            b2[i]   = (const float*)d_in[6 + 4 * i + 3];
        }
    }
    unsigned short* wsb = (unsigned short*)d_ws;   // needs ~16 MB of workspace
    sort_pid<<<3, 256, 0, stream>>>(pid[0], pid[1], pid[2], wsb);
    gather_prep<<<4224, 256, 0, stream>>>(feat[0], feat[1], feat[2],
                                          w1[0], w1[1], w1[2],
                                          w2[0], w2[1], w2[2], wsb);
    fused_mlp<<<384, 256, 0, stream>>>(b1[0], b1[1], b1[2],
                                       b2[0], b2[1], b2[2],
                                       wsb, (float*)d_out);
}

// Round 4
// 521.901 us; speedup vs baseline: 1.0796x; 1.0214x over previous
//
#include <hip/hip_runtime.h>

typedef __attribute__((ext_vector_type(8))) short short8;
typedef __attribute__((ext_vector_type(4))) float floatx4;
typedef __attribute__((ext_vector_type(4))) unsigned int uintx4;

__device__ __forceinline__ short f2bf(float f) {
    unsigned u = __builtin_bit_cast(unsigned, f);
    u = (u + 0x7FFFu + ((u >> 16) & 1u)) >> 16;
    return (short)u;
}

// ---------------------------------------------------------------------------
// Workspace layout (bf16 element offsets):
//   w1T0=0, w1T1=65536, w1T2=196608, w2T0=458752, w2T1=524288, w2T2=589824
//   xg0 = 655360  (4096*256)
//   xg1 = 1703936 (4096*512)
//   xg2 = 3801088 (4096*1024)
//   sorted pid (int2, 3 scales x 256) @ bf16 offset 7995392 (byte 15990784)
// ---------------------------------------------------------------------------

// Bitonic sort of 256 (s, p) pairs per scale, ascending by s.
__global__ __launch_bounds__(256) void sort_pid(
    const int* __restrict__ pid0, const int* __restrict__ pid1, const int* __restrict__ pid2,
    unsigned short* __restrict__ wsb)
{
    __shared__ int ks[256];
    __shared__ int vs[256];
    const int* pid = (blockIdx.x == 0) ? pid0 : (blockIdx.x == 1) ? pid1 : pid2;
    int t = threadIdx.x;
    ks[t] = pid[t];
    vs[t] = t;
    __syncthreads();
    for (int k = 2; k <= 256; k <<= 1) {
        for (int j = k >> 1; j > 0; j >>= 1) {
            int ixj = t ^ j;
            if (ixj > t) {
                int a = ks[t], b = ks[ixj];
                bool asc = ((t & k) == 0);
                if (asc ? (a > b) : (a < b)) {
                    ks[t] = b; ks[ixj] = a;
                    int va = vs[t]; vs[t] = vs[ixj]; vs[ixj] = va;
                }
            }
            __syncthreads();
        }
    }
    int2* sp = (int2*)(wsb + 7995392) + blockIdx.x * 256;
    sp[t] = make_int2(ks[t], vs[t]);
}

// ---------------------------------------------------------------------------
// Sample-major gather. Block = (scale, b, 64-channel group [, sample-half]).
// Read phase: wave w owns channels [w*16, w*16+16); its 64 lanes read 64
//   CONSECUTIVE SORTED samples per load -> ascending addresses within one
//   plane -> intra-wave line merging; all samples sharing a 128B line are
//   consumed by the same instruction (deterministic reuse, no L2 luck).
// Write phase: LDS transpose tile[64c][256s] -> per-thread 128B contiguous
//   store to compact x[row][C] (row slot from sort permutation).
// Blocks [0,512): gather (scale0 x128 heavy-first, scale1 x128, scale2 x256).
// Blocks [512,1152): weight transpose+cast (overlaps the gather).
// ---------------------------------------------------------------------------
template<int NCH>   // sample chunks of 64 handled per lane (2 or 4)
__device__ __forceinline__ void gather_body(
    const float* __restrict__ featb, const int2* __restrict__ sp,
    unsigned short* __restrict__ xg, int C, int HW, int b, int cg, int sh,
    unsigned short (*tile)[256], int t)
{
    int wid = t >> 6, lane = t & 63;
    int s0 = sh * 128;
    int sj[NCH];
    #pragma unroll
    for (int j = 0; j < NCH; ++j) sj[j] = sp[s0 + j * 64 + lane].x;

    int cbase = cg * 64 + wid * 16;
    #pragma unroll 2
    for (int cl = 0; cl < 16; ++cl) {
        const float* plane = featb + (size_t)(cbase + cl) * HW;
        float v[NCH];
        #pragma unroll
        for (int j = 0; j < NCH; ++j) v[j] = plane[sj[j]];
        #pragma unroll
        for (int j = 0; j < NCH; ++j)
            tile[wid * 16 + cl][j * 64 + lane] = (unsigned short)f2bf(v[j]);
    }
    __syncthreads();
    if (t < NCH * 64) {
        int2 e = sp[s0 + t];                    // (s, original p)
        int row = b * 256 + e.y;
        short8 rv[8];
        #pragma unroll
        for (int c8 = 0; c8 < 8; ++c8)
            #pragma unroll
            for (int k = 0; k < 8; ++k)
                rv[c8][k] = (short)tile[c8 * 8 + k][t];
        unsigned short* dst = xg + (size_t)row * C + cg * 64;
        #pragma unroll
        for (int c8 = 0; c8 < 8; ++c8)
            *(short8*)(dst + c8 * 8) = rv[c8];   // 128B contiguous, line-aligned
    }
}

__global__ __launch_bounds__(256) void gather_prep(
    const float* __restrict__ feat0, const float* __restrict__ feat1, const float* __restrict__ feat2,
    const float* __restrict__ w10, const float* __restrict__ w11, const float* __restrict__ w12,
    const float* __restrict__ w20, const float* __restrict__ w21, const float* __restrict__ w22,
    unsigned short* __restrict__ wsb)
{
    __shared__ unsigned short tile[64][256];
    __shared__ float wt[32][33];
    int blk = blockIdx.x;
    int t = threadIdx.x;

    if (blk >= 512) {
        // ---- weight transpose+cast fp32 w[K][256] -> bf16 wT[256][K] ----
        blk -= 512;
        const float* in; unsigned short* out; int K, t0;
        if (blk < 64)       { in = w10; out = wsb;          K = 256;  t0 = 0; }
        else if (blk < 192) { in = w11; out = wsb + 65536;  K = 512;  t0 = 64; }
        else if (blk < 448) { in = w12; out = wsb + 196608; K = 1024; t0 = 192; }
        else if (blk < 512) { in = w20; out = wsb + 458752; K = 256;  t0 = 448; }
        else if (blk < 576) { in = w21; out = wsb + 524288; K = 256;  t0 = 512; }
        else                { in = w22; out = wsb + 589824; K = 256;  t0 = 576; }
        int tile_id = blk - t0;
        int tk = K >> 5;
        int k0 = (tile_id % tk) << 5;
        int n0 = (tile_id / tk) << 5;
        int j = t & 31, i0 = (t >> 5) << 2;
        #pragma unroll
        for (int u = 0; u < 4; u++)
            wt[i0 + u][j] = in[(size_t)(k0 + i0 + u) * 256 + (n0 + j)];
        __syncthreads();
        int kf = t & 31, nf0 = (t >> 5) << 2;
        #pragma unroll
        for (int u = 0; u < 4; u++)
            out[(size_t)(n0 + nf0 + u) * K + (k0 + kf)] = (unsigned short)f2bf(wt[kf][nf0 + u]);
        return;
    }

    const int2* spb = (const int2*)(wsb + 7995392);
    if (blk < 128) {            // scale0: 16 b x 4 cg x 2 sample-halves
        int b = blk >> 3, r = blk & 7, cg = r >> 1, sh = r & 1;
        const float* featb = feat0 + (size_t)b * 256 * 16384;
        gather_body<2>(featb, spb, wsb + 655360, 256, 16384, b, cg, sh, tile, t);
    } else if (blk < 256) {     // scale1: 16 b x 8 cg
        int l = blk - 128, b = l >> 3, cg = l & 7;
        const float* featb = feat1 + (size_t)b * 512 * 4096;
        gather_body<4>(featb, spb + 256, wsb + 1703936, 512, 4096, b, cg, 0, tile, t);
    } else {                    // scale2: 16 b x 16 cg
        int l = blk - 256, b = l >> 4, cg = l & 15;
        const float* featb = feat2 + (size_t)b * 1024 * 1024;
        gather_body<4>(featb, spb + 512, wsb + 3801088, 1024, 1024, b, cg, 0, tile, t);
    }
}

// ---------------------------------------------------------------------------
// MLP(2-layer, relu) + L2-normalize, reading compact bf16 x from workspace.
// Block: 32 rows x 256 cols. 4 waves: wave w -> rows (w&1)*16, cols (w>>1)*128.
// ---------------------------------------------------------------------------
__global__ __launch_bounds__(256, 2) void fused_mlp(
    const float* __restrict__ b1_0, const float* __restrict__ b1_1, const float* __restrict__ b1_2,
    const float* __restrict__ b2_0, const float* __restrict__ b2_1, const float* __restrict__ b2_2,
    const unsigned short* __restrict__ wsb,
    float* __restrict__ out)
{
    __shared__ __align__(16) unsigned short smem[26944];
    unsigned short* wsS = smem;            // 256*72
    unsigned short* xs  = smem + 18432;    // 32*72
    unsigned short* hs  = smem + 18432;    // 32*264
    float* rs = (float*)(smem + 26880);    // 32 floats

    int blk = blockIdx.x;
    int scale = 2 - (blk >> 7);            // big-K blocks dispatched first
    int mblk = blk & 127;

    const float* b1; const float* b2;
    const unsigned short* w1T; const unsigned short* w2T; const unsigned short* xg;
    int C; size_t outBase;
    if (scale == 0) { b1 = b1_0; b2 = b2_0; w1T = wsb;          w2T = wsb + 458752;
                      xg = wsb + 655360;  C = 256;  outBase = 0; }
    else if (scale == 1) { b1 = b1_1; b2 = b2_1; w1T = wsb + 65536;  w2T = wsb + 524288;
                      xg = wsb + 1703936; C = 512;  outBase = 1048576; }
    else            { b1 = b1_2; b2 = b2_2; w1T = wsb + 196608; w2T = wsb + 589824;
                      xg = wsb + 3801088; C = 1024; outBase = 2097152; }

    int t = threadIdx.x;
    int wid = t >> 6, lane = t & 63, quad = lane >> 4, l15 = lane & 15;
    int r0 = (wid & 1) << 4;          // row offset of this wave
    int c0 = (wid >> 1) << 7;         // col offset of this wave

    int gr = t >> 3;                  // 0..31
    int gk = (t & 7) << 3;            // 0,8,...,56
    int row_g = (mblk << 5) + gr;
    const unsigned short* xrow = xg + (size_t)row_g * C;

    floatx4 acc[8];
    #pragma unroll
    for (int f = 0; f < 8; f++) acc[f] = (floatx4){0.f, 0.f, 0.f, 0.f};

    // ---------------- GEMM1: x[32,C] @ w1[C,256] ----------------
    for (int kc = 0; kc < C; kc += 64) {
        *(short8*)(xs + gr * 72 + gk) = *(const short8*)(xrow + kc + gk);
        {
            const uintx4* src = (const uintx4*)(w1T + (size_t)t * C + kc);
            uintx4* dst = (uintx4*)(wsS + t * 72);
            #pragma unroll
            for (int j2 = 0; j2 < 8; j2++) dst[j2] = src[j2];
        }
        __syncthreads();
        const unsigned short* aRow = xs + (r0 + l15) * 72;
        const unsigned short* bRow = wsS + (c0 + l15) * 72;
        #pragma unroll
        for (int ks = 0; ks < 2; ks++) {
            short8 af = *(const short8*)(aRow + ks * 32 + quad * 8);
            #pragma unroll
            for (int f = 0; f < 8; f++) {
                short8 bf = *(const short8*)(bRow + f * (16 * 72) + ks * 32 + quad * 8);
                acc[f] = __builtin_amdgcn_mfma_f32_16x16x32_bf16(af, bf, acc[f], 0, 0, 0);
            }
        }
        __syncthreads();
    }

    // ---------------- h = relu(acc + b1) -> LDS (bf16) ----------------
    {
        float bias1[8];
        #pragma unroll
        for (int f = 0; f < 8; f++) bias1[f] = b1[c0 + f * 16 + l15];
        #pragma unroll
        for (int f = 0; f < 8; f++)
            #pragma unroll
            for (int reg = 0; reg < 4; reg++) {
                float h = fmaxf(acc[f][reg] + bias1[f], 0.f);
                hs[(r0 + quad * 4 + reg) * 264 + (c0 + f * 16 + l15)] = (unsigned short)f2bf(h);
            }
    }

    // ---------------- GEMM2: h[32,256] @ w2[256,256] ----------------
    #pragma unroll
    for (int f = 0; f < 8; f++) acc[f] = (floatx4){0.f, 0.f, 0.f, 0.f};
    const unsigned short* hA = hs + (r0 + l15) * 264;
    for (int kc = 0; kc < 256; kc += 64) {
        {
            const uintx4* src = (const uintx4*)(w2T + (size_t)t * 256 + kc);
            uintx4* dst = (uintx4*)(wsS + t * 72);
            #pragma unroll
            for (int j2 = 0; j2 < 8; j2++) dst[j2] = src[j2];
        }
        __syncthreads();
        const unsigned short* bRow = wsS + (c0 + l15) * 72;
        #pragma unroll
        for (int ks = 0; ks < 2; ks++) {
            short8 af = *(const short8*)(hA + kc + ks * 32 + quad * 8);
            #pragma unroll
            for (int f = 0; f < 8; f++) {
                short8 bf = *(const short8*)(bRow + f * (16 * 72) + ks * 32 + quad * 8);
                acc[f] = __builtin_amdgcn_mfma_f32_16x16x32_bf16(af, bf, acc[f], 0, 0, 0);
            }
        }
        __syncthreads();
    }

    // ---------------- epilogue: y = acc + b2; y / (||y|| + 1e-7) ----------------
    {
        float bias2[8];
        #pragma unroll
        for (int f = 0; f < 8; f++) bias2[f] = b2[c0 + f * 16 + l15];
        float psq[4] = {0.f, 0.f, 0.f, 0.f};
        #pragma unroll
        for (int f = 0; f < 8; f++)
            #pragma unroll
            for (int reg = 0; reg < 4; reg++) {
                float yv = acc[f][reg] + bias2[f];
                acc[f][reg] = yv;
                psq[reg] += yv * yv;
            }
        #pragma unroll
        for (int m = 1; m < 16; m <<= 1)
            #pragma unroll
            for (int reg = 0; reg < 4; reg++)
                psq[reg] += __shfl_xor(psq[reg], m, 16);

        if (t < 32) rs[t] = 0.f;
        __syncthreads();
        if (l15 == 0) {
            #pragma unroll
            for (int reg = 0; reg < 4; reg++)
                atomicAdd(&rs[r0 + quad * 4 + reg], psq[reg]);
        }
        __syncthreads();

        #pragma unroll
        for (int f = 0; f < 8; f++)
            #pragma unroll
            for (int reg = 0; reg < 4; reg++) {
                int row = r0 + quad * 4 + reg;
                float inv = 1.f / (sqrtf(rs[row]) + 1e-7f);
                out[outBase + (size_t)((mblk << 5) + row) * 256 + (c0 + f * 16 + l15)] =
                    acc[f][reg] * inv;
            }
    }
}

extern "C" void kernel_launch(void* const* d_in, const int* in_sizes, int n_in,
                              void* d_out, int out_size, void* d_ws, size_t ws_size,
                              hipStream_t stream)
{
    (void)n_in; (void)out_size; (void)ws_size;
    bool dict = (in_sizes[1] == 256);
    const float *feat[3], *w1[3], *b1[3], *w2[3], *b2[3];
    const int* pid[3];
    for (int i = 0; i < 3; i++) {
        if (dict) {
            feat[i] = (const float*)d_in[i * 6 + 0];
            pid[i]  = (const int*)  d_in[i * 6 + 1];
            w1[i]   = (const float*)d_in[i * 6 + 2];
            b1[i]   = (const float*)d_in[i * 6 + 3];
            w2[i]   = (const float*)d_in[i * 6 + 4];
            b2[i]   = (const float*)d_in[i * 6 + 5];
        } else {
            feat[i] = (const float*)d_in[i];
            pid[i]  = (const int*)  d_in[3 + i];
            w1[i]   = (const float*)d_in[6 + 4 * i + 0];
            b1[i]   = (const float*)d_in[6 + 4 * i + 1];
            w2[i]   = (const float*)d_in[6 + 4 * i + 2];
            b2[i]   = (const float*)d_in[6 + 4 * i + 3];
        }
    }
    unsigned short* wsb = (unsigned short*)d_ws;   // needs ~16 MB of workspace
    sort_pid<<<3, 256, 0, stream>>>(pid[0], pid[1], pid[2], wsb);
    gather_prep<<<1152, 256, 0, stream>>>(feat[0], feat[1], feat[2],
                                          w1[0], w1[1], w1[2],
                                          w2[0], w2[1], w2[2], wsb);
    fused_mlp<<<384, 256, 0, stream>>>(b1[0], b1[1], b1[2],
                                       b2[0], b2[1], b2[2],
                                       wsb, (float*)d_out);
}